// Round 1
// baseline (2023.102 us; speedup 1.0000x reference)
//
#include <hip/hip_runtime.h>
#include <stdint.h>

// ---------- types & helpers ----------
typedef __attribute__((ext_vector_type(8))) short bf16x8;   // 8 bf16 = 4 VGPRs
typedef __attribute__((ext_vector_type(4))) float f32x4;    // MFMA C/D frag

__device__ __forceinline__ f32x4 mfma16(bf16x8 a, bf16x8 b, f32x4 c) {
  return __builtin_amdgcn_mfma_f32_16x16x32_bf16(a, b, c, 0, 0, 0);
}

__device__ __forceinline__ uint16_t f2b(float f) {          // f32 -> bf16 RNE
  uint32_t u = __builtin_bit_cast(uint32_t, f);
  return (uint16_t)((u + 0x7FFFu + ((u >> 16) & 1u)) >> 16);
}
__device__ __forceinline__ float b2f(uint16_t b) {
  return __builtin_bit_cast(float, (uint32_t)b << 16);
}

// Layouts (all bf16 unless noted):
//  F   : [B][H+2][W+2][832]  feat, halo-padded. ch 0:256 x, 256:512 r, 512:801 corr, 801:832 zero
//  rpt : [B][H+16][W+16][256] padded ref (pad 8 each side)
//  Map : [B][H+2][W+2][256]  map conv output, halo-padded
//  Wm  : [9][256 o][832 k],  Wo : [9][256 o][256 k]
//  out : NCHW fp32 [2][256][H][W] per level, concatenated

// ---------- pack x/ref -> F channels + rpt ----------
template<int H, int W>
__global__ void pack_xr(const float* __restrict__ x, const float* __restrict__ r,
                        uint16_t* __restrict__ F, uint16_t* __restrict__ rpt) {
  constexpr int NP = 2 * H * W;
  int t = blockIdx.x * 256 + threadIdx.x;          // total NP*32
  int pix = t % NP;
  int g = t / NP;                                  // channel group (8 ch)
  int b = pix / (H * W), h = (pix / W) % H, w = pix % W;
  int c0 = g * 8;
  const float* xp = x + ((size_t)(b * 256 + c0) * H + h) * W + w;
  const float* rp = r + ((size_t)(b * 256 + c0) * H + h) * W + w;
  bf16x8 vx, vr;
#pragma unroll
  for (int j = 0; j < 8; j++) {
    vx[j] = (short)f2b(xp[(size_t)j * H * W]);
    vr[j] = (short)f2b(rp[(size_t)j * H * W]);
  }
  size_t fpix = (size_t)((b * (H + 2) + h + 1) * (W + 2) + (w + 1)) * 832;
  *(bf16x8*)(F + fpix + c0) = vx;
  *(bf16x8*)(F + fpix + 256 + c0) = vr;
  size_t rpix = (size_t)((b * (H + 16) + h + 8) * (W + 16) + (w + 8)) * 256;
  *(bf16x8*)(rpt + rpix + c0) = vr;
}

// ---------- correlation via banded MFMA GEMM ----------
// wave handles 16 consecutive pixels of one row; D[p][u] = x[p] . refrow[w0+u], u in [0,32)
template<int H, int W>
__global__ void corr_k(uint16_t* F, const uint16_t* __restrict__ rpt) {
  constexpr int WT = W / 16;
  int tile = blockIdx.x * 4 + (threadIdx.x >> 6);
  int lane = threadIdx.x & 63, quad = lane >> 4, n16 = lane & 15;
  int b = tile / (H * WT), h = (tile / WT) % H, w0 = (tile % WT) * 16;

  const uint16_t* xb = F + (size_t)((b * (H + 2) + h + 1) * (W + 2) + (w0 + n16 + 1)) * 832 + quad * 8;
  bf16x8 a[8];
#pragma unroll
  for (int ks = 0; ks < 8; ks++) a[ks] = *(const bf16x8*)(xb + ks * 32);

  for (int di = 0; di < 17; di++) {
    const uint16_t* rr = rpt + (size_t)((b * (H + 16) + h + di) * (W + 16) + w0) * 256 + quad * 8;
    f32x4 ac0 = {0.f, 0.f, 0.f, 0.f}, ac1 = {0.f, 0.f, 0.f, 0.f};
#pragma unroll
    for (int ks = 0; ks < 8; ks++) {
      bf16x8 b0 = *(const bf16x8*)(rr + (size_t)n16 * 256 + ks * 32);
      bf16x8 b1 = *(const bf16x8*)(rr + (size_t)(n16 + 16) * 256 + ks * 32);
      ac0 = mfma16(a[ks], b0, ac0);
      ac1 = mfma16(a[ks], b1, ac1);
    }
#pragma unroll
    for (int rI = 0; rI < 4; rI++) {
      int p = quad * 4 + rI;
      uint16_t* wp = F + (size_t)((b * (H + 2) + h + 1) * (W + 2) + (w0 + p + 1)) * 832 + 512 + di * 17;
      int dj0 = n16 - p;
      if (dj0 >= 0 && dj0 <= 16) wp[dj0] = f2b(ac0[rI]);
      int dj1 = n16 + 16 - p;                     // always >= 1
      if (dj1 <= 16) wp[dj1] = f2b(ac1[rI]);
    }
  }
}

// ---------- weight repack: w[o][Kin][3][3] fp32 -> [tap][o][Kpad] bf16 (zero-pad k) ----------
__global__ void pack_w(const float* __restrict__ w, uint16_t* __restrict__ out, int Kin, int Kpad) {
  int t = blockIdx.x * 256 + threadIdx.x;          // total 256*Kpad
  int k = t % Kpad, o = t / Kpad;
  if (o >= 256) return;
  if (k < Kin) {
    const float* s = w + ((size_t)o * Kin + k) * 9;
#pragma unroll
    for (int tap = 0; tap < 9; tap++) out[((size_t)tap * 256 + o) * Kpad + k] = f2b(s[tap]);
  } else {
#pragma unroll
    for (int tap = 0; tap < 9; tap++) out[((size_t)tap * 256 + o) * Kpad + k] = 0;
  }
}

// ---------- map conv: out[pix][o], A=feat(pix,k) B=Wm(k,o); wave = 32 pix x 64 o ----------
template<int H, int W>
__global__ void map_conv(const uint16_t* __restrict__ F, const uint16_t* __restrict__ Wm,
                         const float* __restrict__ bias, uint16_t* __restrict__ Map) {
  int wave = threadIdx.x >> 6;
  int lane = threadIdx.x & 63, quad = lane >> 4, n16 = lane & 15;
  int pixbase = blockIdx.x * 128 + wave * 32;
  int obase = blockIdx.y * 64;

  const uint16_t* Abase[2];
#pragma unroll
  for (int mt = 0; mt < 2; mt++) {
    int pix = pixbase + mt * 16 + n16;
    int b = pix / (H * W), h = (pix / W) % H, w = pix % W;
    Abase[mt] = F + (size_t)((b * (H + 2) + h + 1) * (W + 2) + (w + 1)) * 832 + quad * 8;
  }
  const uint16_t* Bbase = Wm + (size_t)(obase + n16) * 832 + quad * 8;

  f32x4 acc[2][4] = {};
  for (int tap = 0; tap < 9; tap++) {
    int dy = tap / 3, dx = tap % 3;
    int aoff = ((dy - 1) * (W + 2) + (dx - 1)) * 832;
    const uint16_t* bt = Bbase + (size_t)tap * 256 * 832;
    for (int ks = 0; ks < 26; ks++) {
      bf16x8 a0 = *(const bf16x8*)(Abase[0] + aoff + ks * 32);
      bf16x8 a1 = *(const bf16x8*)(Abase[1] + aoff + ks * 32);
#pragma unroll
      for (int nt = 0; nt < 4; nt++) {
        bf16x8 bb = *(const bf16x8*)(bt + (size_t)nt * 16 * 832 + ks * 32);
        acc[0][nt] = mfma16(a0, bb, acc[0][nt]);
        acc[1][nt] = mfma16(a1, bb, acc[1][nt]);
      }
    }
  }
#pragma unroll
  for (int mt = 0; mt < 2; mt++) {
#pragma unroll
    for (int rI = 0; rI < 4; rI++) {
      int pix = pixbase + mt * 16 + quad * 4 + rI;
      int b = pix / (H * W), h = (pix / W) % H, w = pix % W;
      uint16_t* mp = Map + (size_t)((b * (H + 2) + h + 1) * (W + 2) + (w + 1)) * 256 + obase;
#pragma unroll
      for (int nt = 0; nt < 4; nt++) {
        int o = obase + nt * 16 + n16;
        mp[nt * 16 + n16] = f2b(acc[mt][nt][rI] + bias[o]);
      }
    }
  }
}

// ---------- FPN nearest-upsample add: fine += up(coarse) ----------
template<int HF, int WF>
__global__ void fpn_add(uint16_t* __restrict__ fine, const uint16_t* __restrict__ coarse) {
  constexpr int HC = HF / 2, WC = WF / 2;
  int t = blockIdx.x * 256 + threadIdx.x;          // total 2*HF*WF*32
  int g = t & 31, pix = t >> 5;
  int b = pix / (HF * WF), h = (pix / WF) % HF, w = pix % WF;
  uint16_t* fp = fine + (size_t)((b * (HF + 2) + h + 1) * (WF + 2) + (w + 1)) * 256 + g * 8;
  const uint16_t* cp = coarse + (size_t)((b * (HC + 2) + (h >> 1) + 1) * (WC + 2) + ((w >> 1) + 1)) * 256 + g * 8;
  bf16x8 fv = *(bf16x8*)fp;
  bf16x8 cv = *(const bf16x8*)cp;
  bf16x8 ov;
#pragma unroll
  for (int j = 0; j < 8; j++) ov[j] = (short)f2b(b2f((uint16_t)fv[j]) + b2f((uint16_t)cv[j]));
  *(bf16x8*)fp = ov;
}

// ---------- out conv: out[o][pix], A=Wo(o,k) B=map(k,pix); wave = 32 o x 64 pix ----------
template<int H, int W>
__global__ void out_conv(const uint16_t* __restrict__ Map, const uint16_t* __restrict__ Wo,
                         const float* __restrict__ bias, float* __restrict__ out) {
  int wave = threadIdx.x >> 6;
  int lane = threadIdx.x & 63, quad = lane >> 4, n16 = lane & 15;
  int obase = blockIdx.y * 128 + wave * 32;
  int pixbase = blockIdx.x * 64;

  const uint16_t* Ab = Wo + (size_t)(obase + n16) * 256 + quad * 8;
  const uint16_t* Bbase[4];
#pragma unroll
  for (int nt = 0; nt < 4; nt++) {
    int pix = pixbase + nt * 16 + n16;
    int b = pix / (H * W), h = (pix / W) % H, w = pix % W;
    Bbase[nt] = Map + (size_t)((b * (H + 2) + h + 1) * (W + 2) + (w + 1)) * 256 + quad * 8;
  }
  f32x4 acc[2][4] = {};
  for (int tap = 0; tap < 9; tap++) {
    int dy = tap / 3, dx = tap % 3;
    int boff = ((dy - 1) * (W + 2) + (dx - 1)) * 256;
    const uint16_t* at = Ab + (size_t)tap * 256 * 256;
    for (int ks = 0; ks < 8; ks++) {
      bf16x8 a0 = *(const bf16x8*)(at + ks * 32);
      bf16x8 a1 = *(const bf16x8*)(at + 16 * 256 + ks * 32);
#pragma unroll
      for (int nt = 0; nt < 4; nt++) {
        bf16x8 bb = *(const bf16x8*)(Bbase[nt] + boff + ks * 32);
        acc[0][nt] = mfma16(a0, bb, acc[0][nt]);
        acc[1][nt] = mfma16(a1, bb, acc[1][nt]);
      }
    }
  }
#pragma unroll
  for (int mt = 0; mt < 2; mt++) {
#pragma unroll
    for (int rI = 0; rI < 4; rI++) {
      int o = obase + mt * 16 + quad * 4 + rI;
      float bv = bias[o];
#pragma unroll
      for (int nt = 0; nt < 4; nt++) {
        int pix = pixbase + nt * 16 + n16;
        int b = pix / (H * W), h = (pix / W) % H, w = pix % W;
        out[((size_t)(b * 256 + o) * H + h) * W + w] = acc[mt][nt][rI] + bv;
      }
    }
  }
}

// ---------- host-side per-level drivers ----------
template<int H>
static void run_pre(const float* x, const float* rx, const float* wmw, const float* bmw,
                    uint16_t* F, uint16_t* rpt, uint16_t* Wmp, uint16_t* Map, hipStream_t s) {
  constexpr int W = H;
  constexpr int NP = 2 * H * W;
  pack_xr<H, W><<<NP * 32 / 256, 256, 0, s>>>(x, rx, F, rpt);
  corr_k<H, W><<<(2 * H * (W / 16)) / 4, 256, 0, s>>>(F, rpt);
  pack_w<<<832, 256, 0, s>>>(wmw, Wmp, 801, 832);
  map_conv<H, W><<<dim3(NP / 128, 4), 256, 0, s>>>(F, Wmp, bmw, Map);
}

template<int H>
static void run_out(const uint16_t* Map, const float* wow, const float* bow,
                    uint16_t* Wop, float* out, hipStream_t s) {
  constexpr int W = H;
  constexpr int NP = 2 * H * W;
  pack_w<<<256, 256, 0, s>>>(wow, Wop, 256, 256);
  out_conv<H, W><<<dim3(NP / 64, 2), 256, 0, s>>>(Map, Wop, bow, out);
}

extern "C" void kernel_launch(void* const* d_in, const int* in_sizes, int n_in,
                              void* d_out, int out_size, void* d_ws, size_t ws_size,
                              hipStream_t stream) {
  const float* x[4]  = {(const float*)d_in[0], (const float*)d_in[2], (const float*)d_in[4], (const float*)d_in[6]};
  const float* rx[4] = {(const float*)d_in[1], (const float*)d_in[3], (const float*)d_in[5], (const float*)d_in[7]};
  const float *wm[4], *bm[4], *wo[4], *bo[4];
  for (int l = 0; l < 4; l++) {
    wm[l] = (const float*)d_in[8 + 4 * l];
    bm[l] = (const float*)d_in[9 + 4 * l];
    wo[l] = (const float*)d_in[10 + 4 * l];
    bo[l] = (const float*)d_in[11 + 4 * l];
  }
  const int Hs[4] = {128, 64, 32, 16};

  char* p = (char*)d_ws;
  auto carve = [&](size_t elems) {
    uint16_t* r = (uint16_t*)p;
    p += ((elems * 2) + 255) & ~(size_t)255;
    return r;
  };
  char* z0 = p;
  uint16_t *F[4], *rpt[4], *Map[4];
  for (int l = 0; l < 4; l++) { int H = Hs[l]; F[l]   = carve((size_t)2 * (H + 2)  * (H + 2)  * 832); }
  for (int l = 0; l < 4; l++) { int H = Hs[l]; rpt[l] = carve((size_t)2 * (H + 16) * (H + 16) * 256); }
  for (int l = 0; l < 4; l++) { int H = Hs[l]; Map[l] = carve((size_t)2 * (H + 2)  * (H + 2)  * 256); }
  size_t zbytes = (size_t)(p - z0);
  uint16_t *Wmp[4], *Wop[4];
  for (int l = 0; l < 4; l++) Wmp[l] = carve((size_t)9 * 256 * 832);
  for (int l = 0; l < 4; l++) Wop[l] = carve((size_t)9 * 256 * 256);

  hipMemsetAsync(z0, 0, zbytes, stream);   // zeros: halos, rpt pad, k-pad channels

  float* out = (float*)d_out;
  float* outp[4] = {out, out + 8388608, out + 10485760, out + 11010048};

  run_pre<128>(x[0], rx[0], wm[0], bm[0], F[0], rpt[0], Wmp[0], Map[0], stream);
  run_pre<64> (x[1], rx[1], wm[1], bm[1], F[1], rpt[1], Wmp[1], Map[1], stream);
  run_pre<32> (x[2], rx[2], wm[2], bm[2], F[2], rpt[2], Wmp[2], Map[2], stream);
  run_pre<16> (x[3], rx[3], wm[3], bm[3], F[3], rpt[3], Wmp[3], Map[3], stream);

  fpn_add<32, 32>  <<<256, 256, 0, stream>>>(Map[2], Map[3]);
  fpn_add<64, 64>  <<<1024, 256, 0, stream>>>(Map[1], Map[2]);
  fpn_add<128, 128><<<4096, 256, 0, stream>>>(Map[0], Map[1]);

  run_out<128>(Map[0], wo[0], bo[0], Wop[0], outp[0], stream);
  run_out<64> (Map[1], wo[1], bo[1], Wop[1], outp[1], stream);
  run_out<32> (Map[2], wo[2], bo[2], Wop[2], outp[2], stream);
  run_out<16> (Map[3], wo[3], bo[3], Wop[3], outp[3], stream);
}

// Round 2
// 1196.022 us; speedup vs baseline: 1.6915x; 1.6915x over previous
//
#include <hip/hip_runtime.h>
#include <stdint.h>

// ---------- types & helpers ----------
typedef __attribute__((ext_vector_type(8))) short bf16x8;   // 8 bf16 = 4 VGPRs
typedef __attribute__((ext_vector_type(4))) float f32x4;    // MFMA C/D frag

__device__ __forceinline__ f32x4 mfma16(bf16x8 a, bf16x8 b, f32x4 c) {
  return __builtin_amdgcn_mfma_f32_16x16x32_bf16(a, b, c, 0, 0, 0);
}

__device__ __forceinline__ uint16_t f2b(float f) {          // f32 -> bf16 RNE
  uint32_t u = __builtin_bit_cast(uint32_t, f);
  return (uint16_t)((u + 0x7FFFu + ((u >> 16) & 1u)) >> 16);
}
__device__ __forceinline__ float b2f(uint16_t b) {
  return __builtin_bit_cast(float, (uint32_t)b << 16);
}

// async global->LDS, 16B per lane. LDS dest must be wave-uniform base + lane*16.
__device__ __forceinline__ void gld16(const uint16_t* g, uint16_t* l) {
  __builtin_amdgcn_global_load_lds(
      (const __attribute__((address_space(1))) void*)g,
      (__attribute__((address_space(3))) void*)l, 16, 0, 0);
}

// Layouts (all bf16 unless noted):
//  F   : [B][H+2][W+2][832]  feat, halo-padded. ch 0:256 x, 256:512 r, 512:801 corr, 801:832 zero
//  rpt : [B][H+16][W+16][256] padded ref (pad 8 each side)
//  Map : [B][H+2][W+2][256]  map conv output, halo-padded
//  Wm  : [9][256 o][832 k],  Wo : [9][256 o][256 k]
//  out : NCHW fp32 [2][256][H][W] per level, concatenated

// ---------- pack x/ref -> F channels + rpt ----------
template<int H, int W>
__global__ void pack_xr(const float* __restrict__ x, const float* __restrict__ r,
                        uint16_t* __restrict__ F, uint16_t* __restrict__ rpt) {
  constexpr int NP = 2 * H * W;
  int t = blockIdx.x * 256 + threadIdx.x;          // total NP*32
  int pix = t % NP;
  int g = t / NP;                                  // channel group (8 ch)
  int b = pix / (H * W), h = (pix / W) % H, w = pix % W;
  int c0 = g * 8;
  const float* xp = x + ((size_t)(b * 256 + c0) * H + h) * W + w;
  const float* rp = r + ((size_t)(b * 256 + c0) * H + h) * W + w;
  bf16x8 vx, vr;
#pragma unroll
  for (int j = 0; j < 8; j++) {
    vx[j] = (short)f2b(xp[(size_t)j * H * W]);
    vr[j] = (short)f2b(rp[(size_t)j * H * W]);
  }
  size_t fpix = (size_t)((b * (H + 2) + h + 1) * (W + 2) + (w + 1)) * 832;
  *(bf16x8*)(F + fpix + c0) = vx;
  *(bf16x8*)(F + fpix + 256 + c0) = vr;
  size_t rpix = (size_t)((b * (H + 16) + h + 8) * (W + 16) + (w + 8)) * 256;
  *(bf16x8*)(rpt + rpix + c0) = vr;
}

// ---------- correlation via banded MFMA GEMM ----------
template<int H, int W>
__global__ void corr_k(uint16_t* F, const uint16_t* __restrict__ rpt) {
  constexpr int WT = W / 16;
  int tile = blockIdx.x * 4 + (threadIdx.x >> 6);
  int lane = threadIdx.x & 63, quad = lane >> 4, n16 = lane & 15;
  int b = tile / (H * WT), h = (tile / WT) % H, w0 = (tile % WT) * 16;

  const uint16_t* xb = F + (size_t)((b * (H + 2) + h + 1) * (W + 2) + (w0 + n16 + 1)) * 832 + quad * 8;
  bf16x8 a[8];
#pragma unroll
  for (int ks = 0; ks < 8; ks++) a[ks] = *(const bf16x8*)(xb + ks * 32);

  for (int di = 0; di < 17; di++) {
    const uint16_t* rr = rpt + (size_t)((b * (H + 16) + h + di) * (W + 16) + w0) * 256 + quad * 8;
    f32x4 ac0 = {0.f, 0.f, 0.f, 0.f}, ac1 = {0.f, 0.f, 0.f, 0.f};
#pragma unroll
    for (int ks = 0; ks < 8; ks++) {
      bf16x8 b0 = *(const bf16x8*)(rr + (size_t)n16 * 256 + ks * 32);
      bf16x8 b1 = *(const bf16x8*)(rr + (size_t)(n16 + 16) * 256 + ks * 32);
      ac0 = mfma16(a[ks], b0, ac0);
      ac1 = mfma16(a[ks], b1, ac1);
    }
#pragma unroll
    for (int rI = 0; rI < 4; rI++) {
      int p = quad * 4 + rI;
      uint16_t* wp = F + (size_t)((b * (H + 2) + h + 1) * (W + 2) + (w0 + p + 1)) * 832 + 512 + di * 17;
      int dj0 = n16 - p;
      if (dj0 >= 0 && dj0 <= 16) wp[dj0] = f2b(ac0[rI]);
      int dj1 = n16 + 16 - p;
      if (dj1 <= 16) wp[dj1] = f2b(ac1[rI]);
    }
  }
}

// ---------- weight repack: w[o][Kin][3][3] fp32 -> [tap][o][Kpad] bf16 ----------
__global__ void pack_w(const float* __restrict__ w, uint16_t* __restrict__ out, int Kin, int Kpad) {
  int t = blockIdx.x * 256 + threadIdx.x;
  int k = t % Kpad, o = t / Kpad;
  if (o >= 256) return;
  if (k < Kin) {
    const float* s = w + ((size_t)o * Kin + k) * 9;
#pragma unroll
    for (int tap = 0; tap < 9; tap++) out[((size_t)tap * 256 + o) * Kpad + k] = f2b(s[tap]);
  } else {
#pragma unroll
    for (int tap = 0; tap < 9; tap++) out[((size_t)tap * 256 + o) * Kpad + k] = 0;
  }
}

// ---------- tiled implicit-GEMM conv (m97 structure) ----------
// 128 pixels x 128 outputs per 256-thread block. K = 9 taps * CK.
// LDS: A 128x32, B 128x32 bf16, XOR-swizzled chunk slots (2-way max, free).
// TO_MAP: store bf16 to haloed Map; else fp32 NCHW to Out.
template<int H, int W, int CK, bool TO_MAP>
__global__ __launch_bounds__(256)
void conv_tiled(const uint16_t* __restrict__ A, const uint16_t* __restrict__ Wt,
                const float* __restrict__ bias,
                uint16_t* __restrict__ Map, float* __restrict__ Out) {
  __shared__ uint16_t lA[128 * 32];
  __shared__ uint16_t lB[128 * 32];

  int tid = threadIdx.x;
  int wave = tid >> 6, lane = tid & 63, quad = lane >> 4, n16 = lane & 15;
  int pixbase = blockIdx.x * 128;
  int obase = blockIdx.y * 128;

  // staging role: rows r0 and r0+64, 16B chunk c0 (swizzled)
  int r0 = tid >> 2, c0 = tid & 3;
  int sw = (r0 >> 1) & 3;                         // same for r0 and r0+64
  auto pixoff = [&](int p) {
    int b = p / (H * W), h = (p / W) % H, w = p % W;
    return (size_t)((b * (H + 2) + h + 1) * (W + 2) + (w + 1));
  };
  const uint16_t* gA0 = A + pixoff(pixbase + r0) * CK + (c0 ^ sw) * 8;
  const uint16_t* gA1 = A + pixoff(pixbase + r0 + 64) * CK + (c0 ^ sw) * 8;
  const uint16_t* gB0 = Wt + (size_t)(obase + r0) * CK + (c0 ^ sw) * 8;
  const uint16_t* gB1 = Wt + (size_t)(obase + r0 + 64) * CK + (c0 ^ sw) * 8;
  uint16_t* dA0 = lA + r0 * 32 + c0 * 8;
  uint16_t* dA1 = lA + (r0 + 64) * 32 + c0 * 8;
  uint16_t* dB0 = lB + r0 * 32 + c0 * 8;
  uint16_t* dB1 = lB + (r0 + 64) * 32 + c0 * 8;

  int mb = (wave & 1) * 64, nb = (wave >> 1) * 64;
  f32x4 acc[4][4] = {};

  for (int tap = 0; tap < 9; tap++) {
    const int aoff = ((tap / 3 - 1) * (W + 2) + (tap % 3 - 1)) * CK;
    const size_t woff = (size_t)tap * 256 * CK;
#pragma unroll 1
    for (int c = 0; c < CK / 32; c++) {
      int kb = c * 32;
      gld16(gA0 + aoff + kb, dA0);
      gld16(gA1 + aoff + kb, dA1);
      gld16(gB0 + woff + kb, dB0);
      gld16(gB1 + woff + kb, dB1);
      __syncthreads();                             // drains vmcnt before barrier

      bf16x8 af[4], bfr[4];
#pragma unroll
      for (int mt = 0; mt < 4; mt++) {
        int row = mb + mt * 16 + n16;
        af[mt] = *(const bf16x8*)&lA[row * 32 + ((quad ^ ((row >> 1) & 3)) * 8)];
      }
#pragma unroll
      for (int nt = 0; nt < 4; nt++) {
        int row = nb + nt * 16 + n16;
        bfr[nt] = *(const bf16x8*)&lB[row * 32 + ((quad ^ ((row >> 1) & 3)) * 8)];
      }
#pragma unroll
      for (int mt = 0; mt < 4; mt++)
#pragma unroll
        for (int nt = 0; nt < 4; nt++)
          acc[mt][nt] = mfma16(af[mt], bfr[nt], acc[mt][nt]);
      __syncthreads();
    }
  }

#pragma unroll
  for (int mt = 0; mt < 4; mt++) {
#pragma unroll
    for (int rI = 0; rI < 4; rI++) {
      int pix = pixbase + mb + mt * 16 + quad * 4 + rI;
      int b = pix / (H * W), h = (pix / W) % H, w = pix % W;
      if (TO_MAP) {
        uint16_t* mp = Map + pixoff(pix) * 256 + obase + nb;
#pragma unroll
        for (int nt = 0; nt < 4; nt++) {
          int o = obase + nb + nt * 16 + n16;
          mp[nt * 16 + n16] = f2b(acc[mt][nt][rI] + bias[o]);
        }
      } else {
#pragma unroll
        for (int nt = 0; nt < 4; nt++) {
          int o = obase + nb + nt * 16 + n16;
          Out[((size_t)(b * 256 + o) * H + h) * W + w] = acc[mt][nt][rI] + bias[o];
        }
      }
    }
  }
}

// ---------- FPN nearest-upsample add: fine += up(coarse) ----------
template<int HF, int WF>
__global__ void fpn_add(uint16_t* __restrict__ fine, const uint16_t* __restrict__ coarse) {
  constexpr int HC = HF / 2, WC = WF / 2;
  int t = blockIdx.x * 256 + threadIdx.x;
  int g = t & 31, pix = t >> 5;
  int b = pix / (HF * WF), h = (pix / WF) % HF, w = pix % WF;
  uint16_t* fp = fine + (size_t)((b * (HF + 2) + h + 1) * (WF + 2) + (w + 1)) * 256 + g * 8;
  const uint16_t* cp = coarse + (size_t)((b * (HC + 2) + (h >> 1) + 1) * (WC + 2) + ((w >> 1) + 1)) * 256 + g * 8;
  bf16x8 fv = *(bf16x8*)fp;
  bf16x8 cv = *(const bf16x8*)cp;
  bf16x8 ov;
#pragma unroll
  for (int j = 0; j < 8; j++) ov[j] = (short)f2b(b2f((uint16_t)fv[j]) + b2f((uint16_t)cv[j]));
  *(bf16x8*)fp = ov;
}

// ---------- host-side per-level drivers ----------
template<int H>
static void run_pre(const float* x, const float* rx, const float* wmw, const float* bmw,
                    uint16_t* F, uint16_t* rpt, uint16_t* Wmp, uint16_t* Map, hipStream_t s) {
  constexpr int W = H;
  constexpr int NP = 2 * H * W;
  pack_xr<H, W><<<NP * 32 / 256, 256, 0, s>>>(x, rx, F, rpt);
  corr_k<H, W><<<(2 * H * (W / 16)) / 4, 256, 0, s>>>(F, rpt);
  pack_w<<<832, 256, 0, s>>>(wmw, Wmp, 801, 832);
  conv_tiled<H, W, 832, true><<<dim3(NP / 128, 2), 256, 0, s>>>(F, Wmp, bmw, Map, nullptr);
}

template<int H>
static void run_out(const uint16_t* Map, const float* wow, const float* bow,
                    uint16_t* Wop, float* out, hipStream_t s) {
  constexpr int W = H;
  constexpr int NP = 2 * H * W;
  pack_w<<<256, 256, 0, s>>>(wow, Wop, 256, 256);
  conv_tiled<H, W, 256, false><<<dim3(NP / 128, 2), 256, 0, s>>>(Map, Wop, bow, nullptr, out);
}

extern "C" void kernel_launch(void* const* d_in, const int* in_sizes, int n_in,
                              void* d_out, int out_size, void* d_ws, size_t ws_size,
                              hipStream_t stream) {
  const float* x[4]  = {(const float*)d_in[0], (const float*)d_in[2], (const float*)d_in[4], (const float*)d_in[6]};
  const float* rx[4] = {(const float*)d_in[1], (const float*)d_in[3], (const float*)d_in[5], (const float*)d_in[7]};
  const float *wm[4], *bm[4], *wo[4], *bo[4];
  for (int l = 0; l < 4; l++) {
    wm[l] = (const float*)d_in[8 + 4 * l];
    bm[l] = (const float*)d_in[9 + 4 * l];
    wo[l] = (const float*)d_in[10 + 4 * l];
    bo[l] = (const float*)d_in[11 + 4 * l];
  }
  const int Hs[4] = {128, 64, 32, 16};

  char* p = (char*)d_ws;
  auto carve = [&](size_t elems) {
    uint16_t* r = (uint16_t*)p;
    p += ((elems * 2) + 255) & ~(size_t)255;
    return r;
  };
  char* z0 = p;
  uint16_t *F[4], *rpt[4], *Map[4];
  for (int l = 0; l < 4; l++) { int H = Hs[l]; F[l]   = carve((size_t)2 * (H + 2)  * (H + 2)  * 832); }
  for (int l = 0; l < 4; l++) { int H = Hs[l]; rpt[l] = carve((size_t)2 * (H + 16) * (H + 16) * 256); }
  for (int l = 0; l < 4; l++) { int H = Hs[l]; Map[l] = carve((size_t)2 * (H + 2)  * (H + 2)  * 256); }
  size_t zbytes = (size_t)(p - z0);
  uint16_t *Wmp[4], *Wop[4];
  for (int l = 0; l < 4; l++) Wmp[l] = carve((size_t)9 * 256 * 832);
  for (int l = 0; l < 4; l++) Wop[l] = carve((size_t)9 * 256 * 256);

  hipMemsetAsync(z0, 0, zbytes, stream);   // zeros: halos, rpt pad, k-pad channels

  float* out = (float*)d_out;
  float* outp[4] = {out, out + 8388608, out + 10485760, out + 11010048};

  run_pre<128>(x[0], rx[0], wm[0], bm[0], F[0], rpt[0], Wmp[0], Map[0], stream);
  run_pre<64> (x[1], rx[1], wm[1], bm[1], F[1], rpt[1], Wmp[1], Map[1], stream);
  run_pre<32> (x[2], rx[2], wm[2], bm[2], F[2], rpt[2], Wmp[2], Map[2], stream);
  run_pre<16> (x[3], rx[3], wm[3], bm[3], F[3], rpt[3], Wmp[3], Map[3], stream);

  fpn_add<32, 32>  <<<256, 256, 0, stream>>>(Map[2], Map[3]);
  fpn_add<64, 64>  <<<1024, 256, 0, stream>>>(Map[1], Map[2]);
  fpn_add<128, 128><<<4096, 256, 0, stream>>>(Map[0], Map[1]);

  run_out<128>(Map[0], wo[0], bo[0], Wop[0], outp[0], stream);
  run_out<64> (Map[1], wo[1], bo[1], Wop[1], outp[1], stream);
  run_out<32> (Map[2], wo[2], bo[2], Wop[2], outp[2], stream);
  run_out<16> (Map[3], wo[3], bo[3], Wop[3], outp[3], stream);
}

// Round 4
// 637.300 us; speedup vs baseline: 3.1745x; 1.8767x over previous
//
#include <hip/hip_runtime.h>
#include <stdint.h>

// ---------- types & helpers ----------
typedef __attribute__((ext_vector_type(8))) short bf16x8;   // 8 bf16 = 4 VGPRs
typedef __attribute__((ext_vector_type(4))) float f32x4;    // MFMA C/D frag

__device__ __forceinline__ f32x4 mfma16(bf16x8 a, bf16x8 b, f32x4 c) {
  return __builtin_amdgcn_mfma_f32_16x16x32_bf16(a, b, c, 0, 0, 0);
}

__device__ __forceinline__ uint16_t f2b(float f) {          // f32 -> bf16 RNE
  uint32_t u = __builtin_bit_cast(uint32_t, f);
  return (uint16_t)((u + 0x7FFFu + ((u >> 16) & 1u)) >> 16);
}
__device__ __forceinline__ float b2f(uint16_t b) {
  return __builtin_bit_cast(float, (uint32_t)b << 16);
}

// async global->LDS, 16B per lane. LDS dest = wave-uniform base + lane*16.
__device__ __forceinline__ void gld16(const uint16_t* g, uint16_t* l) {
  __builtin_amdgcn_global_load_lds(
      (const __attribute__((address_space(1))) void*)g,
      (__attribute__((address_space(3))) void*)l, 16, 0, 0);
}

// Layouts (all bf16 unless noted):
//  F   : [B][H+2][W+2][832]  feat, halo-padded. ch 0:256 x, 256:512 r, 512:801 corr, 801:832 zero
//  rpt : [B][H+16][W+16][256] padded ref (pad 8 each side)
//  Map : [B][H+2][W+2][256]  map conv output, halo-padded
//  Wm  : [9][256 o][832 k],  Wo : [9][256 o][256 k]
//  out : NCHW fp32 [2][256][H][W] per level, concatenated

// ---------- pack x/ref -> F channels + rpt (round-2 body, level-fused) ----------
template<int H, int W>
__device__ __forceinline__ void pack_xr_body(int local, const float* __restrict__ x,
                                             const float* __restrict__ r,
                                             uint16_t* __restrict__ F, uint16_t* __restrict__ rpt) {
  constexpr int NP = 2 * H * W;
  int t = local * 256 + threadIdx.x;               // total NP*32
  int pix = t % NP;
  int g = t / NP;                                  // channel group (8 ch)
  int b = pix / (H * W), h = (pix / W) % H, w = pix % W;
  int c0 = g * 8;
  const float* xp = x + ((size_t)(b * 256 + c0) * H + h) * W + w;
  const float* rp = r + ((size_t)(b * 256 + c0) * H + h) * W + w;
  bf16x8 vx, vr;
#pragma unroll
  for (int j = 0; j < 8; j++) {
    vx[j] = (short)f2b(xp[(size_t)j * H * W]);
    vr[j] = (short)f2b(rp[(size_t)j * H * W]);
  }
  size_t fpix = (size_t)((b * (H + 2) + h + 1) * (W + 2) + (w + 1)) * 832;
  *(bf16x8*)(F + fpix + c0) = vx;
  *(bf16x8*)(F + fpix + 256 + c0) = vr;
  size_t rpix = (size_t)((b * (H + 16) + h + 8) * (W + 16) + (w + 8)) * 256;
  *(bf16x8*)(rpt + rpix + c0) = vr;
}

__global__ void pack_xr_all(const float* x0, const float* r0, uint16_t* F0, uint16_t* p0,
                            const float* x1, const float* r1, uint16_t* F1, uint16_t* p1,
                            const float* x2, const float* r2, uint16_t* F2, uint16_t* p2,
                            const float* x3, const float* r3, uint16_t* F3, uint16_t* p3) {
  int bx = blockIdx.x;
  if      (bx < 4096) pack_xr_body<128,128>(bx,        x0, r0, F0, p0);
  else if (bx < 5120) pack_xr_body< 64, 64>(bx - 4096, x1, r1, F1, p1);
  else if (bx < 5376) pack_xr_body< 32, 32>(bx - 5120, x2, r2, F2, p2);
  else                pack_xr_body< 16, 16>(bx - 5376, x3, r3, F3, p3);
}

// ---------- correlation via banded MFMA GEMM (round-2 body, level-fused) ----------
template<int H, int W>
__device__ __forceinline__ void corr_body(int local, uint16_t* F, const uint16_t* __restrict__ rpt) {
  constexpr int WT = W / 16;
  int tile = local * 4 + (threadIdx.x >> 6);
  int lane = threadIdx.x & 63, quad = lane >> 4, n16 = lane & 15;
  int b = tile / (H * WT), h = (tile / WT) % H, w0 = (tile % WT) * 16;

  const uint16_t* xb = F + (size_t)((b * (H + 2) + h + 1) * (W + 2) + (w0 + n16 + 1)) * 832 + quad * 8;
  bf16x8 a[8];
#pragma unroll
  for (int ks = 0; ks < 8; ks++) a[ks] = *(const bf16x8*)(xb + ks * 32);

  for (int di = 0; di < 17; di++) {
    const uint16_t* rr = rpt + (size_t)((b * (H + 16) + h + di) * (W + 16) + w0) * 256 + quad * 8;
    f32x4 ac0 = {0.f, 0.f, 0.f, 0.f}, ac1 = {0.f, 0.f, 0.f, 0.f};
#pragma unroll
    for (int ks = 0; ks < 8; ks++) {
      bf16x8 b0 = *(const bf16x8*)(rr + (size_t)n16 * 256 + ks * 32);
      bf16x8 b1 = *(const bf16x8*)(rr + (size_t)(n16 + 16) * 256 + ks * 32);
      ac0 = mfma16(a[ks], b0, ac0);
      ac1 = mfma16(a[ks], b1, ac1);
    }
#pragma unroll
    for (int rI = 0; rI < 4; rI++) {
      int p = quad * 4 + rI;
      uint16_t* wp = F + (size_t)((b * (H + 2) + h + 1) * (W + 2) + (w0 + p + 1)) * 832 + 512 + di * 17;
      int dj0 = n16 - p;
      if (dj0 >= 0 && dj0 <= 16) wp[dj0] = f2b(ac0[rI]);
      int dj1 = n16 + 16 - p;
      if (dj1 <= 16) wp[dj1] = f2b(ac1[rI]);
    }
  }
}

__global__ void corr_all(uint16_t* F0, const uint16_t* p0, uint16_t* F1, const uint16_t* p1,
                         uint16_t* F2, const uint16_t* p2, uint16_t* F3, const uint16_t* p3) {
  int bx = blockIdx.x;
  if      (bx < 512) corr_body<128,128>(bx,       F0, p0);
  else if (bx < 640) corr_body< 64, 64>(bx - 512, F1, p1);
  else if (bx < 672) corr_body< 32, 32>(bx - 640, F2, p2);
  else               corr_body< 16, 16>(bx - 672, F3, p3);
}

// ---------- weight repack (round-2 body): fp32 [o][Kin][3][3] -> bf16 [tap][o][Kpad] ----------
__device__ __forceinline__ void pw_body(int local, const float* __restrict__ w,
                                        uint16_t* __restrict__ out, int Kin, int Kpad) {
  int t = local * 256 + threadIdx.x;
  int k = t % Kpad, o = t / Kpad;
  if (o >= 256) return;
  if (k < Kin) {
    const float* s = w + ((size_t)o * Kin + k) * 9;
#pragma unroll
    for (int tap = 0; tap < 9; tap++) out[((size_t)tap * 256 + o) * Kpad + k] = f2b(s[tap]);
  } else {
#pragma unroll
    for (int tap = 0; tap < 9; tap++) out[((size_t)tap * 256 + o) * Kpad + k] = 0;
  }
}

__global__ void pack_w_all(const float* wm0, const float* wm1, const float* wm2, const float* wm3,
                           const float* wo0, const float* wo1, const float* wo2, const float* wo3,
                           uint16_t* Wm0, uint16_t* Wm1, uint16_t* Wm2, uint16_t* Wm3,
                           uint16_t* Wo0, uint16_t* Wo1, uint16_t* Wo2, uint16_t* Wo3) {
  int bx = blockIdx.x;
  if      (bx <  832) pw_body(bx,        wm0, Wm0, 801, 832);
  else if (bx < 1664) pw_body(bx -  832, wm1, Wm1, 801, 832);
  else if (bx < 2496) pw_body(bx - 1664, wm2, Wm2, 801, 832);
  else if (bx < 3328) pw_body(bx - 2496, wm3, Wm3, 801, 832);
  else if (bx < 3584) pw_body(bx - 3328, wo0, Wo0, 256, 256);
  else if (bx < 3840) pw_body(bx - 3584, wo1, Wo1, 256, 256);
  else if (bx < 4096) pw_body(bx - 3840, wo2, Wo2, 256, 256);
  else                pw_body(bx - 4096, wo3, Wo3, 256, 256);
}

// ---------- tiled implicit-GEMM conv (round-2 body verbatim, level-fused) ----------
template<int H, int W, int CK, bool TO_MAP>
__device__ __forceinline__ void conv_body(uint16_t* lA, uint16_t* lB, int local,
                                          const uint16_t* __restrict__ A, const uint16_t* __restrict__ Wt,
                                          const float* __restrict__ bias,
                                          uint16_t* __restrict__ MapO, float* __restrict__ Out) {
  constexpr int XB = (2 * H * W) / 128;            // pixel-tile count
  int tid = threadIdx.x;
  int wave = tid >> 6, lane = tid & 63, quad = lane >> 4, n16 = lane & 15;
  int pixbase = (local % XB) * 128;
  int obase = (local / XB) * 128;

  int r0 = tid >> 2, c0 = tid & 3;
  int sw = (r0 >> 1) & 3;
  auto pixoff = [&](int p) {
    int b = p / (H * W), h = (p / W) % H, w = p % W;
    return (size_t)((b * (H + 2) + h + 1) * (W + 2) + (w + 1));
  };
  const uint16_t* gA0 = A + pixoff(pixbase + r0) * CK + (c0 ^ sw) * 8;
  const uint16_t* gA1 = A + pixoff(pixbase + r0 + 64) * CK + (c0 ^ sw) * 8;
  const uint16_t* gB0 = Wt + (size_t)(obase + r0) * CK + (c0 ^ sw) * 8;
  const uint16_t* gB1 = Wt + (size_t)(obase + r0 + 64) * CK + (c0 ^ sw) * 8;
  uint16_t* dA0 = lA + r0 * 32 + c0 * 8;
  uint16_t* dA1 = lA + (r0 + 64) * 32 + c0 * 8;
  uint16_t* dB0 = lB + r0 * 32 + c0 * 8;
  uint16_t* dB1 = lB + (r0 + 64) * 32 + c0 * 8;

  int mb = (wave & 1) * 64, nb = (wave >> 1) * 64;
  f32x4 acc[4][4] = {};

  for (int tap = 0; tap < 9; tap++) {
    const int aoff = ((tap / 3 - 1) * (W + 2) + (tap % 3 - 1)) * CK;
    const size_t woff = (size_t)tap * 256 * CK;
#pragma unroll 1
    for (int c = 0; c < CK / 32; c++) {
      int kb = c * 32;
      gld16(gA0 + aoff + kb, dA0);
      gld16(gA1 + aoff + kb, dA1);
      gld16(gB0 + woff + kb, dB0);
      gld16(gB1 + woff + kb, dB1);
      __syncthreads();

      bf16x8 af[4], bfr[4];
#pragma unroll
      for (int mt = 0; mt < 4; mt++) {
        int row = mb + mt * 16 + n16;
        af[mt] = *(const bf16x8*)&lA[row * 32 + ((quad ^ ((row >> 1) & 3)) * 8)];
      }
#pragma unroll
      for (int nt = 0; nt < 4; nt++) {
        int row = nb + nt * 16 + n16;
        bfr[nt] = *(const bf16x8*)&lB[row * 32 + ((quad ^ ((row >> 1) & 3)) * 8)];
      }
#pragma unroll
      for (int mt = 0; mt < 4; mt++)
#pragma unroll
        for (int nt = 0; nt < 4; nt++)
          acc[mt][nt] = mfma16(af[mt], bfr[nt], acc[mt][nt]);
      __syncthreads();
    }
  }

#pragma unroll
  for (int mt = 0; mt < 4; mt++) {
#pragma unroll
    for (int rI = 0; rI < 4; rI++) {
      int pix = pixbase + mb + mt * 16 + quad * 4 + rI;
      int b = pix / (H * W), h = (pix / W) % H, w = pix % W;
      if (TO_MAP) {
        uint16_t* mp = MapO + pixoff(pix) * 256 + obase + nb;
#pragma unroll
        for (int nt = 0; nt < 4; nt++) {
          int o = obase + nb + nt * 16 + n16;
          mp[nt * 16 + n16] = f2b(acc[mt][nt][rI] + bias[o]);
        }
      } else {
#pragma unroll
        for (int nt = 0; nt < 4; nt++) {
          int o = obase + nb + nt * 16 + n16;
          Out[((size_t)(b * 256 + o) * H + h) * W + w] = acc[mt][nt][rI] + bias[o];
        }
      }
    }
  }
}

__global__ __launch_bounds__(256)
void conv_map_all(const uint16_t* F0, const uint16_t* W0, const float* b0, uint16_t* M0,
                  const uint16_t* F1, const uint16_t* W1, const float* b1, uint16_t* M1,
                  const uint16_t* F2, const uint16_t* W2, const float* b2, uint16_t* M2,
                  const uint16_t* F3, const uint16_t* W3, const float* b3, uint16_t* M3) {
  __shared__ uint16_t lA[128 * 32];
  __shared__ uint16_t lB[128 * 32];
  int bx = blockIdx.x;
  if      (bx < 512) conv_body<128,128,832,true>(lA, lB, bx,       F0, W0, b0, M0, nullptr);
  else if (bx < 640) conv_body< 64, 64,832,true>(lA, lB, bx - 512, F1, W1, b1, M1, nullptr);
  else if (bx < 672) conv_body< 32, 32,832,true>(lA, lB, bx - 640, F2, W2, b2, M2, nullptr);
  else               conv_body< 16, 16,832,true>(lA, lB, bx - 672, F3, W3, b3, M3, nullptr);
}

__global__ __launch_bounds__(256)
void conv_out_all(const uint16_t* M0, const uint16_t* W0, const float* b0, float* o0,
                  const uint16_t* M1, const uint16_t* W1, const float* b1, float* o1,
                  const uint16_t* M2, const uint16_t* W2, const float* b2, float* o2,
                  const uint16_t* M3, const uint16_t* W3, const float* b3, float* o3) {
  __shared__ uint16_t lA[128 * 32];
  __shared__ uint16_t lB[128 * 32];
  int bx = blockIdx.x;
  if      (bx < 512) conv_body<128,128,256,false>(lA, lB, bx,       M0, W0, b0, nullptr, o0);
  else if (bx < 640) conv_body< 64, 64,256,false>(lA, lB, bx - 512, M1, W1, b1, nullptr, o1);
  else if (bx < 672) conv_body< 32, 32,256,false>(lA, lB, bx - 640, M2, W2, b2, nullptr, o2);
  else               conv_body< 16, 16,256,false>(lA, lB, bx - 672, M3, W3, b3, nullptr, o3);
}

// ---------- FPN nearest-upsample add: fine += up(coarse) ----------
template<int HF, int WF>
__global__ void fpn_add(uint16_t* __restrict__ fine, const uint16_t* __restrict__ coarse) {
  constexpr int HC = HF / 2, WC = WF / 2;
  int t = blockIdx.x * 256 + threadIdx.x;
  int g = t & 31, pix = t >> 5;
  int b = pix / (HF * WF), h = (pix / WF) % HF, w = pix % WF;
  uint16_t* fp = fine + (size_t)((b * (HF + 2) + h + 1) * (WF + 2) + (w + 1)) * 256 + g * 8;
  const uint16_t* cp = coarse + (size_t)((b * (HC + 2) + (h >> 1) + 1) * (WC + 2) + ((w >> 1) + 1)) * 256 + g * 8;
  bf16x8 fv = *(bf16x8*)fp;
  bf16x8 cv = *(const bf16x8*)cp;
  bf16x8 ov;
#pragma unroll
  for (int j = 0; j < 8; j++) ov[j] = (short)f2b(b2f((uint16_t)fv[j]) + b2f((uint16_t)cv[j]));
  *(bf16x8*)fp = ov;
}

extern "C" void kernel_launch(void* const* d_in, const int* in_sizes, int n_in,
                              void* d_out, int out_size, void* d_ws, size_t ws_size,
                              hipStream_t stream) {
  const float* x[4]  = {(const float*)d_in[0], (const float*)d_in[2], (const float*)d_in[4], (const float*)d_in[6]};
  const float* rx[4] = {(const float*)d_in[1], (const float*)d_in[3], (const float*)d_in[5], (const float*)d_in[7]};
  const float *wm[4], *bm[4], *wo[4], *bo[4];
  for (int l = 0; l < 4; l++) {
    wm[l] = (const float*)d_in[8 + 4 * l];
    bm[l] = (const float*)d_in[9 + 4 * l];
    wo[l] = (const float*)d_in[10 + 4 * l];
    bo[l] = (const float*)d_in[11 + 4 * l];
  }
  const int Hs[4] = {128, 64, 32, 16};

  char* p = (char*)d_ws;
  auto carve = [&](size_t elems) {
    uint16_t* r = (uint16_t*)p;
    p += ((elems * 2) + 255) & ~(size_t)255;
    return r;
  };
  char* z0 = p;
  uint16_t *F[4], *rpt[4], *Map[4];
  for (int l = 0; l < 4; l++) { int H = Hs[l]; F[l]   = carve((size_t)2 * (H + 2)  * (H + 2)  * 832); }
  for (int l = 0; l < 4; l++) { int H = Hs[l]; rpt[l] = carve((size_t)2 * (H + 16) * (H + 16) * 256); }
  for (int l = 0; l < 4; l++) { int H = Hs[l]; Map[l] = carve((size_t)2 * (H + 2)  * (H + 2)  * 256); }
  size_t zbytes = (size_t)(p - z0);
  uint16_t *Wmp[4], *Wop[4];
  for (int l = 0; l < 4; l++) Wmp[l] = carve((size_t)9 * 256 * 832);
  for (int l = 0; l < 4; l++) Wop[l] = carve((size_t)9 * 256 * 256);

  hipMemsetAsync(z0, 0, zbytes, stream);   // zeros: halos, rpt pad, k-pad channels

  float* out = (float*)d_out;
  float* outp[4] = {out, out + 8388608, out + 10485760, out + 11010048};

  pack_w_all<<<4352, 256, 0, stream>>>(wm[0], wm[1], wm[2], wm[3], wo[0], wo[1], wo[2], wo[3],
                                       Wmp[0], Wmp[1], Wmp[2], Wmp[3], Wop[0], Wop[1], Wop[2], Wop[3]);
  pack_xr_all<<<5440, 256, 0, stream>>>(x[0], rx[0], F[0], rpt[0], x[1], rx[1], F[1], rpt[1],
                                        x[2], rx[2], F[2], rpt[2], x[3], rx[3], F[3], rpt[3]);
  corr_all<<<680, 256, 0, stream>>>(F[0], rpt[0], F[1], rpt[1], F[2], rpt[2], F[3], rpt[3]);
  conv_map_all<<<680, 256, 0, stream>>>(F[0], Wmp[0], bm[0], Map[0], F[1], Wmp[1], bm[1], Map[1],
                                        F[2], Wmp[2], bm[2], Map[2], F[3], Wmp[3], bm[3], Map[3]);

  fpn_add<32, 32>  <<<256, 256, 0, stream>>>(Map[2], Map[3]);
  fpn_add<64, 64>  <<<1024, 256, 0, stream>>>(Map[1], Map[2]);
  fpn_add<128, 128><<<4096, 256, 0, stream>>>(Map[0], Map[1]);

  conv_out_all<<<680, 256, 0, stream>>>(Map[0], Wop[0], bo[0], outp[0], Map[1], Wop[1], bo[1], outp[1],
                                        Map[2], Wop[2], bo[2], outp[2], Map[3], Wop[3], bo[3], outp[3]);
}

// Round 5
// 596.942 us; speedup vs baseline: 3.3891x; 1.0676x over previous
//
#include <hip/hip_runtime.h>
#include <stdint.h>

// ---------- types & helpers ----------
typedef __attribute__((ext_vector_type(8))) short bf16x8;   // 8 bf16 = 4 VGPRs
typedef __attribute__((ext_vector_type(4))) float f32x4;    // MFMA C/D frag

__device__ __forceinline__ f32x4 mfma16(bf16x8 a, bf16x8 b, f32x4 c) {
  return __builtin_amdgcn_mfma_f32_16x16x32_bf16(a, b, c, 0, 0, 0);
}

__device__ __forceinline__ uint16_t f2b(float f) {          // f32 -> bf16 RNE
  uint32_t u = __builtin_bit_cast(uint32_t, f);
  return (uint16_t)((u + 0x7FFFu + ((u >> 16) & 1u)) >> 16);
}
__device__ __forceinline__ float b2f(uint16_t b) {
  return __builtin_bit_cast(float, (uint32_t)b << 16);
}

// async global->LDS, 16B per lane. LDS dest = wave-uniform base + lane*16.
__device__ __forceinline__ void gld16(const uint16_t* g, uint16_t* l) {
  __builtin_amdgcn_global_load_lds(
      (const __attribute__((address_space(1))) void*)g,
      (__attribute__((address_space(3))) void*)l, 16, 0, 0);
}

// Layouts (all bf16 unless noted):
//  F   : [B][H+2][W+2][832]  feat, halo-padded. ch 0:256 x, 256:512 r, 512:801 corr, 801:832 zero
//  rpt : [B][H+16][W+16][256] padded ref (pad 8 each side)
//  Map : [B][H+2][W+2][256]  map conv output, halo-padded; Mf: fpn-composed finals
//  Wm  : [9][256 o][832 k],  Wo : [9][256 o][256 k]
//  out : NCHW fp32 [2][256][H][W] per level, concatenated

// ---------- pack x/ref -> F channels + rpt ----------
template<int H, int W>
__device__ __forceinline__ void pack_xr_body(int local, const float* __restrict__ x,
                                             const float* __restrict__ r,
                                             uint16_t* __restrict__ F, uint16_t* __restrict__ rpt) {
  constexpr int NP = 2 * H * W;
  int t = local * 256 + threadIdx.x;               // total NP*32
  int pix = t % NP;
  int g = t / NP;                                  // channel group (8 ch)
  int b = pix / (H * W), h = (pix / W) % H, w = pix % W;
  int c0 = g * 8;
  const float* xp = x + ((size_t)(b * 256 + c0) * H + h) * W + w;
  const float* rp = r + ((size_t)(b * 256 + c0) * H + h) * W + w;
  bf16x8 vx, vr;
#pragma unroll
  for (int j = 0; j < 8; j++) {
    vx[j] = (short)f2b(xp[(size_t)j * H * W]);
    vr[j] = (short)f2b(rp[(size_t)j * H * W]);
  }
  size_t fpix = (size_t)((b * (H + 2) + h + 1) * (W + 2) + (w + 1)) * 832;
  *(bf16x8*)(F + fpix + c0) = vx;
  *(bf16x8*)(F + fpix + 256 + c0) = vr;
  size_t rpix = (size_t)((b * (H + 16) + h + 8) * (W + 16) + (w + 8)) * 256;
  *(bf16x8*)(rpt + rpix + c0) = vr;
}

// ---------- weight repack: fp32 [o][Kin][3][3] -> bf16 [tap][o][Kpad] ----------
__device__ __forceinline__ void pw_body(int local, const float* __restrict__ w,
                                        uint16_t* __restrict__ out, int Kin, int Kpad) {
  int t = local * 256 + threadIdx.x;
  int k = t % Kpad, o = t / Kpad;
  if (o >= 256) return;
  if (k < Kin) {
    const float* s = w + ((size_t)o * Kin + k) * 9;
#pragma unroll
    for (int tap = 0; tap < 9; tap++) out[((size_t)tap * 256 + o) * Kpad + k] = f2b(s[tap]);
  } else {
#pragma unroll
    for (int tap = 0; tap < 9; tap++) out[((size_t)tap * 256 + o) * Kpad + k] = 0;
  }
}

// prep = pack_xr (all levels) + pack_w (all weights), one launch
__global__ void prep_all(const float* x0, const float* r0, uint16_t* F0, uint16_t* p0,
                         const float* x1, const float* r1, uint16_t* F1, uint16_t* p1,
                         const float* x2, const float* r2, uint16_t* F2, uint16_t* p2,
                         const float* x3, const float* r3, uint16_t* F3, uint16_t* p3,
                         const float* wm0, const float* wm1, const float* wm2, const float* wm3,
                         const float* wo0, const float* wo1, const float* wo2, const float* wo3,
                         uint16_t* Wm0, uint16_t* Wm1, uint16_t* Wm2, uint16_t* Wm3,
                         uint16_t* Wo0, uint16_t* Wo1, uint16_t* Wo2, uint16_t* Wo3) {
  int bx = blockIdx.x;
  if      (bx < 4096) pack_xr_body<128,128>(bx,        x0, r0, F0, p0);
  else if (bx < 5120) pack_xr_body< 64, 64>(bx - 4096, x1, r1, F1, p1);
  else if (bx < 5376) pack_xr_body< 32, 32>(bx - 5120, x2, r2, F2, p2);
  else if (bx < 5440) pack_xr_body< 16, 16>(bx - 5376, x3, r3, F3, p3);
  else if (bx < 6272) pw_body(bx - 5440, wm0, Wm0, 801, 832);
  else if (bx < 7104) pw_body(bx - 6272, wm1, Wm1, 801, 832);
  else if (bx < 7936) pw_body(bx - 7104, wm2, Wm2, 801, 832);
  else if (bx < 8768) pw_body(bx - 7936, wm3, Wm3, 801, 832);
  else if (bx < 9024) pw_body(bx - 8768, wo0, Wo0, 256, 256);
  else if (bx < 9280) pw_body(bx - 9024, wo1, Wo1, 256, 256);
  else if (bx < 9536) pw_body(bx - 9280, wo2, Wo2, 256, 256);
  else                pw_body(bx - 9536, wo3, Wo3, 256, 256);
}

// ---------- correlation via banded MFMA GEMM (round-4 body, unchanged) ----------
template<int H, int W>
__device__ __forceinline__ void corr_body(int local, uint16_t* F, const uint16_t* __restrict__ rpt) {
  constexpr int WT = W / 16;
  int tile = local * 4 + (threadIdx.x >> 6);
  int lane = threadIdx.x & 63, quad = lane >> 4, n16 = lane & 15;
  int b = tile / (H * WT), h = (tile / WT) % H, w0 = (tile % WT) * 16;

  const uint16_t* xb = F + (size_t)((b * (H + 2) + h + 1) * (W + 2) + (w0 + n16 + 1)) * 832 + quad * 8;
  bf16x8 a[8];
#pragma unroll
  for (int ks = 0; ks < 8; ks++) a[ks] = *(const bf16x8*)(xb + ks * 32);

  for (int di = 0; di < 17; di++) {
    const uint16_t* rr = rpt + (size_t)((b * (H + 16) + h + di) * (W + 16) + w0) * 256 + quad * 8;
    f32x4 ac0 = {0.f, 0.f, 0.f, 0.f}, ac1 = {0.f, 0.f, 0.f, 0.f};
#pragma unroll
    for (int ks = 0; ks < 8; ks++) {
      bf16x8 b0 = *(const bf16x8*)(rr + (size_t)n16 * 256 + ks * 32);
      bf16x8 b1 = *(const bf16x8*)(rr + (size_t)(n16 + 16) * 256 + ks * 32);
      ac0 = mfma16(a[ks], b0, ac0);
      ac1 = mfma16(a[ks], b1, ac1);
    }
#pragma unroll
    for (int rI = 0; rI < 4; rI++) {
      int p = quad * 4 + rI;
      uint16_t* wp = F + (size_t)((b * (H + 2) + h + 1) * (W + 2) + (w0 + p + 1)) * 832 + 512 + di * 17;
      int dj0 = n16 - p;
      if (dj0 >= 0 && dj0 <= 16) wp[dj0] = f2b(ac0[rI]);
      int dj1 = n16 + 16 - p;
      if (dj1 <= 16) wp[dj1] = f2b(ac1[rI]);
    }
  }
}

__global__ void corr_all(uint16_t* F0, const uint16_t* p0, uint16_t* F1, const uint16_t* p1,
                         uint16_t* F2, const uint16_t* p2, uint16_t* F3, const uint16_t* p3) {
  int bx = blockIdx.x;
  if      (bx < 512) corr_body<128,128>(bx,       F0, p0);
  else if (bx < 640) corr_body< 64, 64>(bx - 512, F1, p1);
  else if (bx < 672) corr_body< 32, 32>(bx - 640, F2, p2);
  else               corr_body< 16, 16>(bx - 672, F3, p3);
}

// ---------- tiled implicit-GEMM conv, dx-shared A staging ----------
// 128 pixels x 128 outputs per 256-thread block. Per (dy, k-chunk):
// stage A once with dx halos (SLOTS = TROWS*(W+2) contiguous haloed pixel-slots,
// lands exactly on the [B][H+2][W+2] buffer bounds) + B for 3 dx taps,
// then 3x16 = 48 MFMA per barrier pair. ds_read:MFMA stays 1:2 (m97 ratio).
template<int H, int W, int CK, bool TO_MAP>
__device__ __forceinline__ void conv_body(uint16_t* lA, uint16_t* lB, int local,
                                          const uint16_t* __restrict__ A, const uint16_t* __restrict__ Wt,
                                          const float* __restrict__ bias,
                                          uint16_t* __restrict__ MapO, float* __restrict__ Out) {
  constexpr int XB = (2 * H * W) / 128;            // pixel-tile count
  constexpr int RS = W + 2;                        // haloed row stride (pixels)
  constexpr int TROWS = 128 / W;                   // image rows per tile
  constexpr int SLOTS = TROWS * RS;                // 130/132/136/144 staged slots
  int tid = threadIdx.x;
  int wave = tid >> 6, lane = tid & 63, quad = lane >> 4, n16 = lane & 15;
  int pixbase = (local % XB) * 128;
  int obase = (local / XB) * 128;

  int b0 = pixbase / (H * W);
  int h0 = (pixbase / W) % H;                      // w0 = 0 (tiles are W-aligned)
  size_t pix0 = ((size_t)(b0 * (H + 2) + h0 + 1)) * RS + 1;  // haloed idx of pixel 0
  size_t abase = (pix0 - 1) * CK;                  // slot 0 (dx=-1 halo) at dy=1

  // staging roles
  int s0 = tid >> 2, c0 = tid & 3;                 // slots s0, s0+64 (sw identical)
  int sw0 = (s0 >> 1) & 3;
  const uint16_t* pA0 = A + abase + (size_t)s0 * CK + (c0 ^ sw0) * 8;
  const uint16_t* pA1 = A + abase + (size_t)(s0 + 64) * CK + (c0 ^ sw0) * 8;
  uint16_t* dA0 = lA + s0 * 32 + c0 * 8;
  uint16_t* dA1 = lA + (s0 + 64) * 32 + c0 * 8;
  // tail slots 128..143 staged by wave 0 only (full wave, lane-ordered dests;
  // global addr clamped for slots >= SLOTS — those LDS slots are never read)
  int s2 = 128 + (lane >> 2), c2 = lane & 3;
  int sg = s2 < SLOTS ? s2 : SLOTS - 1;
  int sw2 = (s2 >> 1) & 3;
  const uint16_t* pA2 = A + abase + (size_t)sg * CK + (c2 ^ sw2) * 8;
  uint16_t* dA2 = lA + s2 * 32 + c2 * 8;

  const uint16_t* pB0 = Wt + (size_t)(obase + s0) * CK + (c0 ^ sw0) * 8;
  const uint16_t* pB1 = Wt + (size_t)(obase + s0 + 64) * CK + (c0 ^ sw0) * 8;
  uint16_t* dBlo = lB + s0 * 32 + c0 * 8;
  uint16_t* dBhi = lB + (s0 + 64) * 32 + c0 * 8;

  int mb = (wave & 1) * 64, nb = (wave >> 1) * 64;
  f32x4 acc[4][4] = {};

  for (int dy = 0; dy < 3; dy++) {
    const ptrdiff_t dyoff = (ptrdiff_t)(dy - 1) * RS * CK;
    const size_t tapbase = (size_t)(dy * 3) * 256 * CK;
#pragma unroll 1
    for (int c = 0; c < CK / 32; c++) {
      int kb = c * 32;
      gld16(pA0 + dyoff + kb, dA0);
      gld16(pA1 + dyoff + kb, dA1);
      if (wave == 0) gld16(pA2 + dyoff + kb, dA2);
      gld16(pB0 + tapbase + kb, dBlo);
      gld16(pB1 + tapbase + kb, dBhi);
      gld16(pB0 + tapbase + (size_t)256 * CK + kb, dBlo + 128 * 32);
      gld16(pB1 + tapbase + (size_t)256 * CK + kb, dBhi + 128 * 32);
      gld16(pB0 + tapbase + (size_t)512 * CK + kb, dBlo + 256 * 32);
      gld16(pB1 + tapbase + (size_t)512 * CK + kb, dBhi + 256 * 32);
      __syncthreads();

#pragma unroll
      for (int dx = 0; dx < 3; dx++) {
        bf16x8 af[4], bfr[4];
#pragma unroll
        for (int mt = 0; mt < 4; mt++) {
          int p = mb + mt * 16 + n16;
          int slot = p + (p / W) * 2 + dx;         // p/W uniform across the 16 lanes
          af[mt] = *(const bf16x8*)&lA[slot * 32 + ((quad ^ ((slot >> 1) & 3)) * 8)];
        }
#pragma unroll
        for (int nt = 0; nt < 4; nt++) {
          int row = nb + nt * 16 + n16;
          bfr[nt] = *(const bf16x8*)&lB[(dx * 128 + row) * 32 + ((quad ^ ((row >> 1) & 3)) * 8)];
        }
#pragma unroll
        for (int mt = 0; mt < 4; mt++)
#pragma unroll
          for (int nt = 0; nt < 4; nt++)
            acc[mt][nt] = mfma16(af[mt], bfr[nt], acc[mt][nt]);
      }
      __syncthreads();
    }
  }

  auto pixoff = [&](int p) {
    int b = p / (H * W), h = (p / W) % H, w = p % W;
    return (size_t)((b * (H + 2) + h + 1) * (W + 2) + (w + 1));
  };
#pragma unroll
  for (int mt = 0; mt < 4; mt++) {
#pragma unroll
    for (int rI = 0; rI < 4; rI++) {
      int pix = pixbase + mb + mt * 16 + quad * 4 + rI;
      int b = pix / (H * W), h = (pix / W) % H, w = pix % W;
      if (TO_MAP) {
        uint16_t* mp = MapO + pixoff(pix) * 256 + obase + nb;
#pragma unroll
        for (int nt = 0; nt < 4; nt++) {
          int o = obase + nb + nt * 16 + n16;
          mp[nt * 16 + n16] = f2b(acc[mt][nt][rI] + bias[o]);
        }
      } else {
#pragma unroll
        for (int nt = 0; nt < 4; nt++) {
          int o = obase + nb + nt * 16 + n16;
          Out[((size_t)(b * 256 + o) * H + h) * W + w] = acc[mt][nt][rI] + bias[o];
        }
      }
    }
  }
}

__global__ __launch_bounds__(256)
void conv_map_all(const uint16_t* F0, const uint16_t* W0, const float* b0, uint16_t* M0,
                  const uint16_t* F1, const uint16_t* W1, const float* b1, uint16_t* M1,
                  const uint16_t* F2, const uint16_t* W2, const float* b2, uint16_t* M2,
                  const uint16_t* F3, const uint16_t* W3, const float* b3, uint16_t* M3) {
  __shared__ uint16_t lA[144 * 32];
  __shared__ uint16_t lB[3 * 128 * 32];
  int bx = blockIdx.x;
  if      (bx < 512) conv_body<128,128,832,true>(lA, lB, bx,       F0, W0, b0, M0, nullptr);
  else if (bx < 640) conv_body< 64, 64,832,true>(lA, lB, bx - 512, F1, W1, b1, M1, nullptr);
  else if (bx < 672) conv_body< 32, 32,832,true>(lA, lB, bx - 640, F2, W2, b2, M2, nullptr);
  else               conv_body< 16, 16,832,true>(lA, lB, bx - 672, F3, W3, b3, M3, nullptr);
}

__global__ __launch_bounds__(256)
void conv_out_all(const uint16_t* M0, const uint16_t* W0, const float* b0, float* o0,
                  const uint16_t* M1, const uint16_t* W1, const float* b1, float* o1,
                  const uint16_t* M2, const uint16_t* W2, const float* b2, float* o2,
                  const uint16_t* M3, const uint16_t* W3, const float* b3, float* o3) {
  __shared__ uint16_t lA[144 * 32];
  __shared__ uint16_t lB[3 * 128 * 32];
  int bx = blockIdx.x;
  if      (bx < 512) conv_body<128,128,256,false>(lA, lB, bx,       M0, W0, b0, nullptr, o0);
  else if (bx < 640) conv_body< 64, 64,256,false>(lA, lB, bx - 512, M1, W1, b1, nullptr, o1);
  else if (bx < 672) conv_body< 32, 32,256,false>(lA, lB, bx - 640, M2, W2, b2, nullptr, o2);
  else               conv_body< 16, 16,256,false>(lA, lB, bx - 672, M3, W3, b3, nullptr, o3);
}

// ---------- composed FPN: Mf_l = sum_{l'>=l} Map_{l'}[h >> (l'-l)] (one launch) ----------
template<int HF, int NS>
__device__ __forceinline__ void fpn_body(int local, const uint16_t* s0, const uint16_t* s1,
                                         const uint16_t* s2, const uint16_t* s3,
                                         uint16_t* __restrict__ dst) {
  int t = local * 256 + threadIdx.x;
  int g = t & 31, pix = t >> 5;
  int b = pix / (HF * HF), h = (pix / HF) % HF, w = pix % HF;
  const uint16_t* srcs[4] = {s0, s1, s2, s3};
  float a[8] = {0, 0, 0, 0, 0, 0, 0, 0};
#pragma unroll
  for (int i = 0; i < NS; i++) {
    int Hc = HF >> i;
    int hc = h >> i, wc = w >> i;
    const uint16_t* p = srcs[i] + ((size_t)(b * (Hc + 2) + hc + 1) * (Hc + 2) + wc + 1) * 256 + g * 8;
    bf16x8 v = *(const bf16x8*)p;
#pragma unroll
    for (int j = 0; j < 8; j++) a[j] += b2f((uint16_t)v[j]);
  }
  bf16x8 o;
#pragma unroll
  for (int j = 0; j < 8; j++) o[j] = (short)f2b(a[j]);
  *(bf16x8*)(dst + ((size_t)(b * (HF + 2) + h + 1) * (HF + 2) + w + 1) * 256 + g * 8) = o;
}

__global__ void fpn_all(const uint16_t* M0, const uint16_t* M1, const uint16_t* M2, const uint16_t* M3,
                        uint16_t* Mf0, uint16_t* Mf1, uint16_t* Mf2) {
  int bx = blockIdx.x;
  if      (bx < 4096) fpn_body<128, 4>(bx,        M0, M1, M2, M3, Mf0);
  else if (bx < 5120) fpn_body< 64, 3>(bx - 4096, M1, M2, M3, nullptr, Mf1);
  else                fpn_body< 32, 2>(bx - 5120, M2, M3, nullptr, nullptr, Mf2);
}

extern "C" void kernel_launch(void* const* d_in, const int* in_sizes, int n_in,
                              void* d_out, int out_size, void* d_ws, size_t ws_size,
                              hipStream_t stream) {
  const float* x[4]  = {(const float*)d_in[0], (const float*)d_in[2], (const float*)d_in[4], (const float*)d_in[6]};
  const float* rx[4] = {(const float*)d_in[1], (const float*)d_in[3], (const float*)d_in[5], (const float*)d_in[7]};
  const float *wm[4], *bm[4], *wo[4], *bo[4];
  for (int l = 0; l < 4; l++) {
    wm[l] = (const float*)d_in[8 + 4 * l];
    bm[l] = (const float*)d_in[9 + 4 * l];
    wo[l] = (const float*)d_in[10 + 4 * l];
    bo[l] = (const float*)d_in[11 + 4 * l];
  }
  const int Hs[4] = {128, 64, 32, 16};

  char* p = (char*)d_ws;
  auto carve = [&](size_t elems) {
    uint16_t* r = (uint16_t*)p;
    p += ((elems * 2) + 255) & ~(size_t)255;
    return r;
  };
  char* z0 = p;
  uint16_t *F[4], *rpt[4], *Map[4], *Mf[3];
  for (int l = 0; l < 4; l++) { int H = Hs[l]; F[l]   = carve((size_t)2 * (H + 2)  * (H + 2)  * 832); }
  for (int l = 0; l < 4; l++) { int H = Hs[l]; rpt[l] = carve((size_t)2 * (H + 16) * (H + 16) * 256); }
  for (int l = 0; l < 4; l++) { int H = Hs[l]; Map[l] = carve((size_t)2 * (H + 2)  * (H + 2)  * 256); }
  for (int l = 0; l < 3; l++) { int H = Hs[l]; Mf[l]  = carve((size_t)2 * (H + 2)  * (H + 2)  * 256); }
  size_t zbytes = (size_t)(p - z0);
  uint16_t *Wmp[4], *Wop[4];
  for (int l = 0; l < 4; l++) Wmp[l] = carve((size_t)9 * 256 * 832);
  for (int l = 0; l < 4; l++) Wop[l] = carve((size_t)9 * 256 * 256);

  hipMemsetAsync(z0, 0, zbytes, stream);   // zeros: halos, rpt pad, k-pad channels

  float* out = (float*)d_out;
  float* outp[4] = {out, out + 8388608, out + 10485760, out + 11010048};

  prep_all<<<9792, 256, 0, stream>>>(x[0], rx[0], F[0], rpt[0], x[1], rx[1], F[1], rpt[1],
                                     x[2], rx[2], F[2], rpt[2], x[3], rx[3], F[3], rpt[3],
                                     wm[0], wm[1], wm[2], wm[3], wo[0], wo[1], wo[2], wo[3],
                                     Wmp[0], Wmp[1], Wmp[2], Wmp[3], Wop[0], Wop[1], Wop[2], Wop[3]);
  corr_all<<<680, 256, 0, stream>>>(F[0], rpt[0], F[1], rpt[1], F[2], rpt[2], F[3], rpt[3]);
  conv_map_all<<<680, 256, 0, stream>>>(F[0], Wmp[0], bm[0], Map[0], F[1], Wmp[1], bm[1], Map[1],
                                        F[2], Wmp[2], bm[2], Map[2], F[3], Wmp[3], bm[3], Map[3]);
  fpn_all<<<5376, 256, 0, stream>>>(Map[0], Map[1], Map[2], Map[3], Mf[0], Mf[1], Mf[2]);
  conv_out_all<<<680, 256, 0, stream>>>(Mf[0], Wop[0], bo[0], outp[0], Mf[1], Wop[1], bo[1], outp[1],
                                        Mf[2], Wop[2], bo[2], outp[2], Map[3], Wop[3], bo[3], outp[3]);
}